// Round 11
// baseline (1177.038 us; speedup 1.0000x reference)
//
#include <hip/hip_runtime.h>

typedef short short8 __attribute__((ext_vector_type(8)));
typedef float f32x4  __attribute__((ext_vector_type(4)));

#define NN 20000
#define NE 60000
#define NB 800
#define NTASK 138
#define EB 256   // edges per keinsum block (64 per wave)
#define NEB 235  // edge blocks = ceil(NE/EB)

static __device__ __forceinline__ float sigm(float x) { return 1.f / (1.f + expf(-x)); }

static __device__ __forceinline__ unsigned short f2bf(float x) {
    unsigned u = __float_as_uint(x);
    unsigned r = (u + 0x7fffu + ((u >> 16) & 1u)) >> 16;
    return (unsigned short)r;
}

// =============== kpre: fused [zero | we2T | seg | fpenc | nodeproj] ===============
__global__ void kpre(float* __restrict__ zbase, int nz4,
                     const float* __restrict__ We2, const float* __restrict__ be2,
                     unsigned short* __restrict__ thi,
                     const int* __restrict__ gid, int* __restrict__ seg,
                     const float* __restrict__ fpv, const float* __restrict__ Wfp,
                     const float* __restrict__ bfpv,
                     const float* __restrict__ bng, const float* __restrict__ bnb,
                     const float* __restrict__ bnm, const float* __restrict__ bnv,
                     float* __restrict__ fpb,
                     const float* __restrict__ nf, const float* __restrict__ Wn,
                     const float* __restrict__ bn, float* __restrict__ hf,
                     unsigned short* __restrict__ hb,
                     int B0, int B1, int B2, int B3) {
    __shared__ float st[64 * 65];       // we2 transpose tile
    __shared__ float sNF[16 * 134];     // nodeproj staging
    __shared__ float sred[128];
    const int bid = blockIdx.x, tid = threadIdx.x;
    if (bid < B0) {
        long base = (long)bid * 2048 + tid;
        #pragma unroll
        for (int r = 0; r < 8; ++r) {
            long i = base + r * 256;
            if (i < nz4) reinterpret_cast<f32x4*>(zbase)[i] = f32x4{0.f, 0.f, 0.f, 0.f};
        }
    } else if (bid < B1) {
        int c = bid - B0;
        const float* srcp = (c < 128) ? We2 + (long)c * 4096 : be2;
        for (int idx = tid; idx < 4096; idx += 256) {
            int o = idx & 63, i = idx >> 6;
            st[o * 65 + i] = srcp[idx];
        }
        __syncthreads();
        for (int idx = tid; idx < 4096; idx += 256) {
            int i = idx & 63, o = idx >> 6;
            thi[(long)c * 4096 + idx] = f2bf(st[o * 65 + i]);
        }
    } else if (bid < B2) {
        int b = (bid - B1) * 256 + tid;
        if (b <= NB) {
            int lo = 0, hi = NN;
            while (lo < hi) { int mid = (lo + hi) >> 1; if (gid[mid] < b) lo = mid + 1; else hi = mid; }
            seg[b] = lo;
        }
    } else if (bid < B3) {
        int g = bid - B2;
        int u = tid & 127, half = tid >> 7;
        float acc = half ? 0.f : bfpv[u];
        const float* fr = fpv + (long)g * 1024 + half * 512;
        const float* wr = Wfp + (long)half * 512 * 128;
        for (int k = 0; k < 512; ++k) acc += fr[k] * wr[k * 128 + u];
        if (half) sred[u] = acc;
        __syncthreads();
        if (!half) {
            acc += sred[u];
            float sc = bng[u] / sqrtf(bnv[u] + 1e-5f);
            fpb[(long)g * 128 + u] = fmaxf((acc - bnm[u]) * sc + bnb[u], 0.f);
        }
    } else {
        int n0 = (bid - B3) * 16;
        const float* nfb = nf + (long)n0 * 134;
        for (int i = tid; i < 16 * 134; i += 256) sNF[i] = nfb[i];
        __syncthreads();
        int u = tid & 63, jg = tid >> 6;
        float a[4];
        float bv = bn[u];
        #pragma unroll
        for (int jj = 0; jj < 4; ++jj) a[jj] = bv;
        for (int k = 0; k < 134; ++k) {
            float w = Wn[k * 64 + u];
            #pragma unroll
            for (int jj = 0; jj < 4; ++jj) a[jj] += sNF[(jg * 4 + jj) * 134 + k] * w;
        }
        #pragma unroll
        for (int jj = 0; jj < 4; ++jj) {
            long o = (long)(n0 + jg * 4 + jj) * 64 + u;
            float v = fmaxf(a[jj], 0.f);
            hf[o] = v;
            hb[o] = f2bf(v);
        }
    }
}

// =============== keinsum v8: 256 edges/block (64/wave), LDS pipeline, fused h@Wres ===============
__global__ __launch_bounds__(256) void keinsum(
    const unsigned short* __restrict__ hb,
    const float* __restrict__ hf, const float* __restrict__ Wres,
    const float* __restrict__ ef, const float* __restrict__ We1, const float* __restrict__ be1,
    const unsigned short* __restrict__ thi,
    const int* __restrict__ src, const int* __restrict__ dst,
    float* __restrict__ agg) {
    __shared__ __align__(16) unsigned short sB[3 * 64 * 72];
    __shared__ __align__(16) float sX[3 * EB];
    __shared__ float sEF[6 * EB];
    const int bid = blockIdx.x, tid = threadIdx.x;
    if (bid >= NEB) {
        // ---- h @ Wres section (atomic) ----
        int t = (bid - NEB) * 256 + tid;
        int u = t & 63;
        int n0 = (t >> 6) * 8;
        if (n0 >= NN) return;
        float a[8] = {0.f, 0.f, 0.f, 0.f, 0.f, 0.f, 0.f, 0.f};
        for (int k = 0; k < 64; ++k) {
            float w = Wres[k * 64 + u];
            #pragma unroll
            for (int j = 0; j < 8; ++j) a[j] += hf[(long)(n0 + j) * 64 + k] * w;
        }
        #pragma unroll
        for (int j = 0; j < 8; ++j) atomicAdd(&agg[(long)(n0 + j) * 64 + u], a[j]);
        return;
    }
    const int lane = tid & 63, wave = tid >> 6;
    const int m = lane & 15, q = lane >> 4;
    const int eb = bid * EB;
    const int e0 = eb + wave * 64;     // 64 edges per wave (4 edge-groups of 16)
    const int c0 = 0, c1 = 129;

    for (int i = tid; i < 6 * EB; i += 256) {
        int e = i / 6, k = i % 6;
        int ee = eb + e; if (ee >= NE) ee = NE - 1;
        sEF[k * EB + e] = ef[(long)ee * 6 + k];
    }

    short8 ahi[4][2];
    #pragma unroll
    for (int eg = 0; eg < 4; ++eg) {
        int em = e0 + eg * 16 + m; if (em >= NE) em = NE - 1;
        int sn = src[em];
        ahi[eg][0] = *reinterpret_cast<const short8*>(hb + (long)sn * 64 + q * 8);
        ahi[eg][1] = *reinterpret_cast<const short8*>(hb + (long)sn * 64 + 32 + q * 8);
    }
    float msg[4][4][4];
    #pragma unroll
    for (int eg = 0; eg < 4; ++eg)
        #pragma unroll
        for (int nt = 0; nt < 4; ++nt)
            #pragma unroll
            for (int r = 0; r < 4; ++r) msg[eg][nt][r] = 0.f;

    short8 rB[2][2];
    auto GLOAD = [&](int c, int setv) {
        const unsigned short* bb = thi + (long)c * 4096;
        #pragma unroll
        for (int it = 0; it < 2; ++it) {
            int u = tid + it * 256;
            rB[setv][it] = *reinterpret_cast<const short8*>(bb + u * 8);
        }
    };
    auto DSW = [&](int buf, int setv, int c) {
        unsigned short* base = &sB[buf * 4608];
        #pragma unroll
        for (int it = 0; it < 2; ++it) {
            int u = tid + it * 256;
            *reinterpret_cast<short8*>(&base[(u >> 3) * 72 + (u & 7) * 8]) = rB[setv][it];
        }
        {
            float xv = 1.f;
            if (c < 128) {
                float a = be1[c];
                #pragma unroll
                for (int k = 0; k < 6; ++k) a += sEF[k * EB + tid] * We1[k * 128 + c];
                xv = fmaxf(a, 0.f);
            }
            sX[buf * EB + tid] = xv;
        }
    };
    auto CMP = [&](int buf) {
        const unsigned short* base = &sB[buf * 4608];
        f32x4 xw[4];
        #pragma unroll
        for (int eg = 0; eg < 4; ++eg)
            xw[eg] = *reinterpret_cast<const f32x4*>(&sX[buf * EB + wave * 64 + eg * 16 + q * 4]);
        short8 b0[4], b1[4];
        #pragma unroll
        for (int nt = 0; nt < 4; ++nt) {
            const unsigned short* rp = &base[(nt * 16 + m) * 72 + q * 8];
            b0[nt] = *reinterpret_cast<const short8*>(rp);
            b1[nt] = *reinterpret_cast<const short8*>(rp + 32);
        }
        #pragma unroll
        for (int eg = 0; eg < 4; ++eg)
            #pragma unroll
            for (int nt = 0; nt < 4; ++nt) {
                f32x4 z = {0.f, 0.f, 0.f, 0.f};
                z = __builtin_amdgcn_mfma_f32_16x16x32_bf16(ahi[eg][0], b0[nt], z, 0, 0, 0);
                z = __builtin_amdgcn_mfma_f32_16x16x32_bf16(ahi[eg][1], b1[nt], z, 0, 0, 0);
                #pragma unroll
                for (int r = 0; r < 4; ++r) msg[eg][nt][r] += xw[eg][r] * z[r];
            }
    };

    GLOAD(c0, 0);
    GLOAD(c0 + 1, 1);
    __syncthreads();
    DSW(0, 0, c0);
    int c = c0;
    for (; c + 1 < c1; c += 2) {
        int s = (c - c0) % 3;
        if (c + 2 < c1) GLOAD(c + 2, 0);
        __syncthreads();
        DSW((s + 1) % 3, 1, c + 1);
        CMP(s);
        if (c + 3 < c1) GLOAD(c + 3, 1);
        __syncthreads();
        if (c + 2 < c1) DSW((s + 2) % 3, 0, c + 2);
        CMP((s + 1) % 3);
    }
    if (c < c1) { __syncthreads(); CMP((c - c0) % 3); }

    #pragma unroll
    for (int eg = 0; eg < 4; ++eg)
        #pragma unroll
        for (int r = 0; r < 4; ++r) {
            int e = e0 + eg * 16 + q * 4 + r;
            if (e < NE) {
                int d = dst[e];
                #pragma unroll
                for (int nt = 0; nt < 4; ++nt)
                    atomicAdd(&agg[(long)d * 64 + nt * 16 + m], msg[eg][nt][r]);
            }
        }
}

// =============== kgruz: LDS-staged GRU (32 nodes/block) + zero next agg ===============
__global__ void kgruz(const float* __restrict__ agg, const float* __restrict__ h,
                      const float* __restrict__ Wgx, const float* __restrict__ bgx,
                      const float* __restrict__ Wgh, const float* __restrict__ bgh,
                      float* __restrict__ hof, unsigned short* __restrict__ hb,
                      float* __restrict__ aggN) {
    const int bid = blockIdx.x, tid = threadIdx.x;
    if (bid >= 625) {
        long base = (long)(bid - 625) * 2048 + tid;
        #pragma unroll
        for (int r = 0; r < 8; ++r) {
            long i = base + r * 256;
            if (i < 320000) reinterpret_cast<f32x4*>(aggN)[i] = f32x4{0.f, 0.f, 0.f, 0.f};
        }
        return;
    }
    __shared__ float sA[2048], sH[2048];
    const int n0 = bid * 32;
    const float* ab = agg + (long)n0 * 64;
    const float* hrow = h + (long)n0 * 64;
    for (int i = tid; i < 2048; i += 256) { sA[i] = ab[i]; sH[i] = hrow[i]; }
    __syncthreads();
    const int u = tid & 63, jg = tid >> 6;
    float xr[8], xz[8], xn[8], hr[8], hz[8], hn[8];
    float b0 = bgx[u], b1 = bgx[64 + u], b2 = bgx[128 + u];
    float d0 = bgh[u], d1 = bgh[64 + u], d2 = bgh[128 + u];
    #pragma unroll
    for (int j = 0; j < 8; ++j) {
        xr[j] = b0; xz[j] = b1; xn[j] = b2;
        hr[j] = d0; hz[j] = d1; hn[j] = d2;
    }
    for (int k = 0; k < 64; ++k) {
        float w0 = Wgx[k * 192 + u], w1 = Wgx[k * 192 + 64 + u], w2 = Wgx[k * 192 + 128 + u];
        float v0 = Wgh[k * 192 + u], v1 = Wgh[k * 192 + 64 + u], v2 = Wgh[k * 192 + 128 + u];
        #pragma unroll
        for (int j = 0; j < 8; ++j) {
            int n = jg * 8 + j;
            float mk = fmaxf(sA[n * 64 + k], 0.f);
            float hk = sH[n * 64 + k];
            xr[j] += mk * w0; xz[j] += mk * w1; xn[j] += mk * w2;
            hr[j] += hk * v0; hz[j] += hk * v1; hn[j] += hk * v2;
        }
    }
    #pragma unroll
    for (int j = 0; j < 8; ++j) {
        int n = jg * 8 + j;
        float rg = sigm(xr[j] + hr[j]);
        float zg = sigm(xz[j] + hz[j]);
        float ng = tanhf(xn[j] + rg * hn[j]);
        long o = (long)(n0 + n) * 64 + u;
        float hv = (1.f - zg) * ng + zg * sH[n * 64 + u];
        hof[o] = hv;
        hb[o] = f2bf(hv);
    }
}

// =============== readout scatter: feat[dst] += [h[src] | relu(ef@Wep+bep)] ===============
__global__ void kreadout(const float* __restrict__ h,
                         const float* __restrict__ ef, const float* __restrict__ Wep,
                         const float* __restrict__ bep,
                         const int* __restrict__ src, const int* __restrict__ dst,
                         float* __restrict__ feat) {
    int t = blockIdx.x * blockDim.x + threadIdx.x;
    if (t >= NE * 128) return;
    int e = t >> 7, j = t & 127;
    float v;
    if (j < 64) {
        v = h[(long)src[e] * 64 + j];
    } else {
        int o = j - 64;
        v = bep[o];
        #pragma unroll
        for (int k = 0; k < 6; ++k) v += ef[(long)e * 6 + k] * Wep[k * 64 + o];
        v = fmaxf(v, 0.f);
    }
    atomicAdd(&feat[(long)dst[e] * 128 + j], v);
}

// =============== fused 3-layer LSTM step; 4 graphs/block, 512 threads ===============
__global__ __launch_bounds__(512) void klstm3(
    const float* __restrict__ qstar,
    const float* __restrict__ Wx0, const float* __restrict__ Wh0, const float* __restrict__ bl0,
    const float* __restrict__ Wx1, const float* __restrict__ Wh1, const float* __restrict__ bl1,
    const float* __restrict__ Wx2, const float* __restrict__ Wh2, const float* __restrict__ bl2,
    const float* __restrict__ h0i, const float* __restrict__ c0i, float* __restrict__ h0o, float* __restrict__ c0o,
    const float* __restrict__ h1i, const float* __restrict__ c1i, float* __restrict__ h1o, float* __restrict__ c1o,
    const float* __restrict__ h2i, const float* __restrict__ c2i, float* __restrict__ h2o, float* __restrict__ c2o) {
    __shared__ float gbuf[4][512];
    const int g = threadIdx.x;
    const int b0g = blockIdx.x * 4;
    const float* Wx[3] = {Wx0, Wx1, Wx2};
    const float* Wh[3] = {Wh0, Wh1, Wh2};
    const float* bl[3] = {bl0, bl1, bl2};
    const float* hin[3] = {h0i, h1i, h2i};
    const float* cin[3] = {c0i, c1i, c2i};
    float* hout[3] = {h0o, h1o, h2o};
    float* cout[3] = {c0o, c1o, c2o};
    for (int l = 0; l < 3; ++l) {
        const int Kx = l ? 128 : 256;
        const float* xb = l ? hout[l - 1] : qstar;
        const int xstride = l ? 128 : 256;
        float acc[4];
        float bv = bl[l][g];
        #pragma unroll
        for (int b = 0; b < 4; ++b) acc[b] = bv;
        const float* wxp = Wx[l];
        for (int k = 0; k < Kx; ++k) {
            float w = wxp[k * 512 + g];
            #pragma unroll
            for (int b = 0; b < 4; ++b) acc[b] += xb[(long)(b0g + b) * xstride + k] * w;
        }
        const float* whp = Wh[l];
        const float* hrow = hin[l];
        for (int k = 0; k < 128; ++k) {
            float w = whp[k * 512 + g];
            #pragma unroll
            for (int b = 0; b < 4; ++b) acc[b] += hrow[(long)(b0g + b) * 128 + k] * w;
        }
        #pragma unroll
        for (int b = 0; b < 4; ++b) gbuf[b][g] = acc[b];
        __syncthreads();
        {
            int b = threadIdx.x >> 7, u = threadIdx.x & 127;
            float gi = gbuf[b][u], gf = gbuf[b][128 + u], gg = gbuf[b][256 + u], go = gbuf[b][384 + u];
            long idx = (long)(b0g + b) * 128 + u;
            float c_ = sigm(gf) * cin[l][idx] + sigm(gi) * tanhf(gg);
            float h_ = sigm(go) * tanhf(c_);
            cout[l][idx] = c_;
            hout[l][idx] = h_;
        }
        __syncthreads();
    }
}

// =============== kattn: fused dot + softmax + weighted sum; 1 block / graph ===============
__global__ __launch_bounds__(256) void kattn(const float* __restrict__ feat,
                                             const float* __restrict__ q,
                                             const int* __restrict__ seg,
                                             float* __restrict__ qstar,
                                             float* __restrict__ esg) {
    const int b = blockIdx.x, tid = threadIdx.x;
    const int s0 = seg[b], s1 = seg[b + 1], len = s1 - s0;
    __shared__ float sq[128];
    __shared__ float ses[128];
    __shared__ float red[256];
    if (tid < 128) {
        float qv = q[(long)b * 128 + tid];
        sq[tid] = qv;
        qstar[(long)b * 256 + tid] = qv;
    }
    __syncthreads();
    const int wave = tid >> 6, lane = tid & 63;
    for (int idx = wave; idx < len; idx += 4) {
        long n = s0 + idx;
        float p = feat[n * 128 + lane] * sq[lane] + feat[n * 128 + 64 + lane] * sq[64 + lane];
        for (int off = 32; off; off >>= 1) p += __shfl_down(p, off, 64);
        if (lane == 0) { if (idx < 128) ses[idx] = p; else esg[n] = p; }
    }
    __syncthreads();
    auto ev = [&](int i) { return i < 128 ? ses[i] : esg[s0 + i]; };
    float lm = -1e30f;
    for (int i = tid; i < len; i += 256) lm = fmaxf(lm, ev(i));
    red[tid] = lm; __syncthreads();
    for (int o = 128; o; o >>= 1) { if (tid < o) red[tid] = fmaxf(red[tid], red[tid + o]); __syncthreads(); }
    float mx = red[0]; __syncthreads();
    float ls = 0.f;
    for (int i = tid; i < len; i += 256) ls += expf(ev(i) - mx);
    red[tid] = ls; __syncthreads();
    for (int o = 128; o; o >>= 1) { if (tid < o) red[tid] += red[tid + o]; __syncthreads(); }
    float inv = 1.f / (red[0] + 1e-9f);
    __syncthreads();
    const int u = tid & 127, par = tid >> 7;
    float racc = 0.f;
    for (int i = par; i < len; i += 2) {
        float wgt = expf(ev(i) - mx) * inv;
        racc += wgt * feat[(long)(s0 + i) * 128 + u];
    }
    if (par == 1) red[u] = racc;
    __syncthreads();
    if (par == 0) {
        racc += red[u];
        qstar[(long)b * 256 + 128 + u] = racc;
    }
}

// =============== khead3: fused FFN (f1 -> f2 -> head); 4 graphs/block, 512 threads ===============
__global__ __launch_bounds__(512) void khead3(const float* __restrict__ qstar,
                                              const float* __restrict__ fpb,
                                              const float* __restrict__ Wf1, const float* __restrict__ bf1,
                                              const float* __restrict__ Wf2, const float* __restrict__ bf2,
                                              const float* __restrict__ Wp, const float* __restrict__ bp,
                                              float* __restrict__ out) {
    __shared__ float sx[4][384];
    __shared__ float s1b[4][300];
    __shared__ float s2[4][256];
    const int tid = threadIdx.x;
    const int b0 = blockIdx.x * 4;
    for (int i = tid; i < 4 * 384; i += 512) {
        int g = i / 384, k = i % 384;
        sx[g][k] = (k < 256) ? qstar[(long)(b0 + g) * 256 + k] : fpb[(long)(b0 + g) * 128 + (k - 256)];
    }
    __syncthreads();
    for (int task = tid; task < 1200; task += 512) {
        int g = task / 300, u = task % 300;
        float acc = bf1[u];
        for (int k = 0; k < 384; ++k) acc += sx[g][k] * Wf1[k * 300 + u];
        s1b[g][u] = fmaxf(acc, 0.f);
    }
    __syncthreads();
    for (int task = tid; task < 1024; task += 512) {
        int g = task >> 8, u = task & 255;
        float acc = bf2[u];
        for (int k = 0; k < 300; ++k) acc += s1b[g][k] * Wf2[k * 256 + u];
        s2[g][u] = fmaxf(acc, 0.f);
    }
    __syncthreads();
    for (int task = tid; task < 4 * NTASK; task += 512) {
        int g = task / NTASK, u = task % NTASK;
        float acc = bp[u];
        for (int k = 0; k < 256; ++k) acc += s2[g][k] * Wp[k * NTASK + u];
        out[(long)(b0 + g) * NTASK + u] = acc;
    }
}

extern "C" void kernel_launch(void* const* d_in, const int* in_sizes, int n_in,
                              void* d_out, int out_size, void* d_ws, size_t ws_size,
                              hipStream_t stream) {
    auto fp_ = [&](int i) { return (const float*)d_in[i]; };
    auto ip_ = [&](int i) { return (const int*)d_in[i]; };
    const float *nf = fp_(0), *ef = fp_(1), *fpv = fp_(2);
    const int *src = ip_(3), *dst = ip_(4), *gid = ip_(5);
    const float *Wn = fp_(6), *bn = fp_(7), *We1 = fp_(8), *be1 = fp_(9);
    const float *We2 = fp_(10), *be2 = fp_(11), *Wres = fp_(12);
    const float *Wgx = fp_(13), *bgx = fp_(14), *Wgh = fp_(15), *bgh = fp_(16);
    const float *Wep = fp_(17), *bep = fp_(18);
    const float *Wlx0 = fp_(19), *Wlh0 = fp_(20), *bl0 = fp_(21);
    const float *Wlx1 = fp_(22), *Wlh1 = fp_(23), *bl1 = fp_(24);
    const float *Wlx2 = fp_(25), *Wlh2 = fp_(26), *bl2 = fp_(27);
    const float *Wfp = fp_(28), *bfpv = fp_(29);
    const float *bng = fp_(30), *bnb = fp_(31), *bnm = fp_(32), *bnv = fp_(33);
    const float *Wf1 = fp_(34), *bf1 = fp_(35), *Wf2 = fp_(36), *bf2 = fp_(37);
    const float *Wp = fp_(38), *bp = fp_(39);

    char* w = (char*)d_ws;
    auto alloc = [&](size_t bytes) -> char* {
        char* p = w; w += (bytes + 255) & ~(size_t)255; return p;
    };
    float* hA = (float*)alloc((size_t)NN * 64 * 4);
    float* hB = (float*)alloc((size_t)NN * 64 * 4);
    unsigned short* hbA = (unsigned short*)alloc((size_t)NN * 64 * 2);
    unsigned short* hbB = (unsigned short*)alloc((size_t)NN * 64 * 2);
    unsigned short* we2thi = (unsigned short*)alloc((size_t)129 * 4096 * 2);
    float* aggB = (float*)alloc((size_t)NN * 64 * 4);   // zeroed by kgruz
    char* zstart = w;                               // ---- zeroed region start ----
    float* aggA  = (float*)alloc((size_t)NN * 64 * 4);
    float* feat  = (float*)alloc((size_t)NN * 128 * 4);
    float* qstar = (float*)alloc((size_t)NB * 256 * 4);
    float* lstmb = (float*)alloc((size_t)12 * NB * 128 * 4);
    size_t zfloats = (size_t)(w - zstart) / 4;      // ---- zeroed region end ----
    float* es   = (float*)alloc((size_t)NN * 4);
    int*   seg  = (int*)alloc((size_t)(NB + 1) * 4);
    float* fpb  = (float*)alloc((size_t)NB * 128 * 4);

    float *hl[3][2], *cl[3][2];
    for (int l = 0; l < 3; ++l)
        for (int a = 0; a < 2; ++a) {
            hl[l][a] = lstmb + ((size_t)(l * 4 + a * 2 + 0)) * NB * 128;
            cl[l][a] = lstmb + ((size_t)(l * 4 + a * 2 + 1)) * NB * 128;
        }

    // --- kpre section boundaries ---
    int nz4 = (int)(zfloats / 4);
    int zb  = (nz4 + 2047) / 2048;
    int B0 = zb;
    int B1 = B0 + 129;            // we2T: 1 block/chunk
    int B2 = B1 + 4;              // seg
    int B3 = B2 + NB;             // fpenc: 1 block/graph
    int B4 = B3 + 1250;           // nodeproj: 16 nodes/block
    kpre<<<B4, 256, 0, stream>>>((float*)zstart, nz4, We2, be2, we2thi, gid, seg,
                                 fpv, Wfp, bfpv, bng, bnb, bnm, bnv, fpb,
                                 nf, Wn, bn, hA, hbA,
                                 B0, B1, B2, B3);

    float* hf[2] = {hA, hB};
    unsigned short* hb[2] = {hbA, hbB};
    float* aggbuf[2] = {aggA, aggB};
    int cur = 0;
    for (int it = 0; it < 3; ++it) {
        float* agg  = aggbuf[it & 1];
        float* aggN = aggbuf[1 - (it & 1)];
        keinsum<<<NEB + 625, 256, 0, stream>>>(hb[cur], hf[cur], Wres,
                                               ef, We1, be1, we2thi, src, dst, agg);
        kgruz<<<625 + 157, 256, 0, stream>>>(agg, hf[cur], Wgx, bgx, Wgh, bgh,
                                             hf[1 - cur], hb[1 - cur], aggN);
        cur = 1 - cur;
    }
    kreadout<<<(NE * 128 + 255) / 256, 256, 0, stream>>>(hf[cur], ef, Wep, bep, src, dst, feat);

    for (int t = 0; t < 6; ++t) {
        int a = t & 1;
        klstm3<<<NB / 4, 512, 0, stream>>>(qstar,
            Wlx0, Wlh0, bl0, Wlx1, Wlh1, bl1, Wlx2, Wlh2, bl2,
            hl[0][a], cl[0][a], hl[0][1 - a], cl[0][1 - a],
            hl[1][a], cl[1][a], hl[1][1 - a], cl[1][1 - a],
            hl[2][a], cl[2][a], hl[2][1 - a], cl[2][1 - a]);
        kattn<<<NB, 256, 0, stream>>>(feat, hl[2][1 - a], seg, qstar, es);
    }
    khead3<<<NB / 4, 512, 0, stream>>>(qstar, fpb, Wf1, bf1, Wf2, bf2, Wp, bp, (float*)d_out);
}

// Round 12
// 1037.907 us; speedup vs baseline: 1.1340x; 1.1340x over previous
//
#include <hip/hip_runtime.h>

typedef short short8 __attribute__((ext_vector_type(8)));
typedef float f32x4  __attribute__((ext_vector_type(4)));

#define NN 20000
#define NE 60000
#define NB 800
#define NTASK 138
#define EB 128   // edges per keinsum block

static __device__ __forceinline__ float sigm(float x) { return 1.f / (1.f + expf(-x)); }

static __device__ __forceinline__ unsigned short f2bf(float x) {
    unsigned u = __float_as_uint(x);
    unsigned r = (u + 0x7fffu + ((u >> 16) & 1u)) >> 16;
    return (unsigned short)r;
}

// =============== kpre: fused [zero | we2T | seg | fpenc | nodeproj] ===============
__global__ void kpre(float* __restrict__ zbase, int nz4,
                     const float* __restrict__ We2, const float* __restrict__ be2,
                     unsigned short* __restrict__ thi,
                     const int* __restrict__ gid, int* __restrict__ seg,
                     const float* __restrict__ fpv, const float* __restrict__ Wfp,
                     const float* __restrict__ bfpv,
                     const float* __restrict__ bng, const float* __restrict__ bnb,
                     const float* __restrict__ bnm, const float* __restrict__ bnv,
                     float* __restrict__ fpb,
                     const float* __restrict__ nf, const float* __restrict__ Wn,
                     const float* __restrict__ bn, float* __restrict__ hf,
                     unsigned short* __restrict__ hb,
                     int B0, int B1, int B2, int B3) {
    __shared__ float st[64 * 65];       // we2 transpose tile
    __shared__ float sNF[16 * 134];     // nodeproj staging
    __shared__ float sred[128];
    const int bid = blockIdx.x, tid = threadIdx.x;
    if (bid < B0) {
        long base = (long)bid * 2048 + tid;
        #pragma unroll
        for (int r = 0; r < 8; ++r) {
            long i = base + r * 256;
            if (i < nz4) reinterpret_cast<f32x4*>(zbase)[i] = f32x4{0.f, 0.f, 0.f, 0.f};
        }
    } else if (bid < B1) {
        int c = bid - B0;
        const float* srcp = (c < 128) ? We2 + (long)c * 4096 : be2;
        for (int idx = tid; idx < 4096; idx += 256) {
            int o = idx & 63, i = idx >> 6;
            st[o * 65 + i] = srcp[idx];
        }
        __syncthreads();
        for (int idx = tid; idx < 4096; idx += 256) {
            int i = idx & 63, o = idx >> 6;
            thi[(long)c * 4096 + idx] = f2bf(st[o * 65 + i]);
        }
    } else if (bid < B2) {
        int b = (bid - B1) * 256 + tid;
        if (b <= NB) {
            int lo = 0, hi = NN;
            while (lo < hi) { int mid = (lo + hi) >> 1; if (gid[mid] < b) lo = mid + 1; else hi = mid; }
            seg[b] = lo;
        }
    } else if (bid < B3) {
        int g = bid - B2;
        int u = tid & 127, half = tid >> 7;
        float acc = half ? 0.f : bfpv[u];
        const float* fr = fpv + (long)g * 1024 + half * 512;
        const float* wr = Wfp + (long)half * 512 * 128;
        for (int k = 0; k < 512; ++k) acc += fr[k] * wr[k * 128 + u];
        if (half) sred[u] = acc;
        __syncthreads();
        if (!half) {
            acc += sred[u];
            float sc = bng[u] / sqrtf(bnv[u] + 1e-5f);
            fpb[(long)g * 128 + u] = fmaxf((acc - bnm[u]) * sc + bnb[u], 0.f);
        }
    } else {
        int n0 = (bid - B3) * 16;
        const float* nfb = nf + (long)n0 * 134;
        for (int i = tid; i < 16 * 134; i += 256) sNF[i] = nfb[i];
        __syncthreads();
        int u = tid & 63, jg = tid >> 6;
        float a[4];
        float bv = bn[u];
        #pragma unroll
        for (int jj = 0; jj < 4; ++jj) a[jj] = bv;
        for (int k = 0; k < 134; ++k) {
            float w = Wn[k * 64 + u];
            #pragma unroll
            for (int jj = 0; jj < 4; ++jj) a[jj] += sNF[(jg * 4 + jj) * 134 + k] * w;
        }
        #pragma unroll
        for (int jj = 0; jj < 4; ++jj) {
            long o = (long)(n0 + jg * 4 + jj) * 64 + u;
            float v = fmaxf(a[jj], 0.f);
            hf[o] = v;
            hb[o] = f2bf(v);
        }
    }
}

// =============== keinsum v7 (R10 proven): 128 edges/block, all 129 chunks, fused h@Wres ===============
__global__ __launch_bounds__(256) void keinsum(
    const unsigned short* __restrict__ hb,
    const float* __restrict__ hf, const float* __restrict__ Wres,
    const float* __restrict__ ef, const float* __restrict__ We1, const float* __restrict__ be1,
    const unsigned short* __restrict__ thi,
    const int* __restrict__ src, const int* __restrict__ dst,
    float* __restrict__ agg) {
    __shared__ __align__(16) unsigned short sB[3 * 64 * 72];
    __shared__ __align__(16) float sX[3 * EB];
    __shared__ float sEF[6 * EB];
    const int bid = blockIdx.x, tid = threadIdx.x;
    if (bid >= 469) {
        // ---- h @ Wres section (atomic) ----
        int t = (bid - 469) * 256 + tid;
        int u = t & 63;
        int n0 = (t >> 6) * 8;
        if (n0 >= NN) return;
        float a[8] = {0.f, 0.f, 0.f, 0.f, 0.f, 0.f, 0.f, 0.f};
        for (int k = 0; k < 64; ++k) {
            float w = Wres[k * 64 + u];
            #pragma unroll
            for (int j = 0; j < 8; ++j) a[j] += hf[(long)(n0 + j) * 64 + k] * w;
        }
        #pragma unroll
        for (int j = 0; j < 8; ++j) atomicAdd(&agg[(long)(n0 + j) * 64 + u], a[j]);
        return;
    }
    const int lane = tid & 63, wave = tid >> 6;
    const int m = lane & 15, q = lane >> 4;
    const int eb = bid * EB;
    const int e0 = eb + wave * 32;
    const int c0 = 0, c1 = 129;

    for (int i = tid; i < 6 * EB; i += 256) {
        int e = i / 6, k = i % 6;
        int ee = eb + e; if (ee >= NE) ee = NE - 1;
        sEF[k * EB + e] = ef[(long)ee * 6 + k];
    }

    short8 ahi[2][2];
    #pragma unroll
    for (int eg = 0; eg < 2; ++eg) {
        int em = e0 + eg * 16 + m; if (em >= NE) em = NE - 1;
        int sn = src[em];
        ahi[eg][0] = *reinterpret_cast<const short8*>(hb + (long)sn * 64 + q * 8);
        ahi[eg][1] = *reinterpret_cast<const short8*>(hb + (long)sn * 64 + 32 + q * 8);
    }
    float msg[2][4][4];
    #pragma unroll
    for (int eg = 0; eg < 2; ++eg)
        #pragma unroll
        for (int nt = 0; nt < 4; ++nt)
            #pragma unroll
            for (int r = 0; r < 4; ++r) msg[eg][nt][r] = 0.f;

    short8 rB[2][2];
    auto GLOAD = [&](int c, int setv) {
        const unsigned short* bb = thi + (long)c * 4096;
        #pragma unroll
        for (int it = 0; it < 2; ++it) {
            int u = tid + it * 256;
            rB[setv][it] = *reinterpret_cast<const short8*>(bb + u * 8);
        }
    };
    auto DSW = [&](int buf, int setv, int c) {
        unsigned short* base = &sB[buf * 4608];
        #pragma unroll
        for (int it = 0; it < 2; ++it) {
            int u = tid + it * 256;
            *reinterpret_cast<short8*>(&base[(u >> 3) * 72 + (u & 7) * 8]) = rB[setv][it];
        }
        if (tid < EB) {
            float xv = 1.f;
            if (c < 128) {
                float a = be1[c];
                #pragma unroll
                for (int k = 0; k < 6; ++k) a += sEF[k * EB + tid] * We1[k * 128 + c];
                xv = fmaxf(a, 0.f);
            }
            sX[buf * EB + tid] = xv;
        }
    };
    auto CMP = [&](int buf) {
        const unsigned short* base = &sB[buf * 4608];
        f32x4 xw[2];
        #pragma unroll
        for (int eg = 0; eg < 2; ++eg)
            xw[eg] = *reinterpret_cast<const f32x4*>(&sX[buf * EB + wave * 32 + eg * 16 + q * 4]);
        short8 b0[4], b1[4];
        #pragma unroll
        for (int nt = 0; nt < 4; ++nt) {
            const unsigned short* rp = &base[(nt * 16 + m) * 72 + q * 8];
            b0[nt] = *reinterpret_cast<const short8*>(rp);
            b1[nt] = *reinterpret_cast<const short8*>(rp + 32);
        }
        #pragma unroll
        for (int eg = 0; eg < 2; ++eg)
            #pragma unroll
            for (int nt = 0; nt < 4; ++nt) {
                f32x4 z = {0.f, 0.f, 0.f, 0.f};
                z = __builtin_amdgcn_mfma_f32_16x16x32_bf16(ahi[eg][0], b0[nt], z, 0, 0, 0);
                z = __builtin_amdgcn_mfma_f32_16x16x32_bf16(ahi[eg][1], b1[nt], z, 0, 0, 0);
                #pragma unroll
                for (int r = 0; r < 4; ++r) msg[eg][nt][r] += xw[eg][r] * z[r];
            }
    };

    GLOAD(c0, 0);
    GLOAD(c0 + 1, 1);
    __syncthreads();
    DSW(0, 0, c0);
    int c = c0;
    for (; c + 1 < c1; c += 2) {
        int s = (c - c0) % 3;
        if (c + 2 < c1) GLOAD(c + 2, 0);
        __syncthreads();
        DSW((s + 1) % 3, 1, c + 1);
        CMP(s);
        if (c + 3 < c1) GLOAD(c + 3, 1);
        __syncthreads();
        if (c + 2 < c1) DSW((s + 2) % 3, 0, c + 2);
        CMP((s + 1) % 3);
    }
    if (c < c1) { __syncthreads(); CMP((c - c0) % 3); }

    #pragma unroll
    for (int eg = 0; eg < 2; ++eg)
        #pragma unroll
        for (int r = 0; r < 4; ++r) {
            int e = e0 + eg * 16 + q * 4 + r;
            if (e < NE) {
                int d = dst[e];
                #pragma unroll
                for (int nt = 0; nt < 4; ++nt)
                    atomicAdd(&agg[(long)d * 64 + nt * 16 + m], msg[eg][nt][r]);
            }
        }
}

// =============== kgruz: LDS-staged GRU (32 nodes/block) + zero next agg ===============
__global__ void kgruz(const float* __restrict__ agg, const float* __restrict__ h,
                      const float* __restrict__ Wgx, const float* __restrict__ bgx,
                      const float* __restrict__ Wgh, const float* __restrict__ bgh,
                      float* __restrict__ hof, unsigned short* __restrict__ hb,
                      float* __restrict__ aggN) {
    const int bid = blockIdx.x, tid = threadIdx.x;
    if (bid >= 625) {
        long base = (long)(bid - 625) * 2048 + tid;
        #pragma unroll
        for (int r = 0; r < 8; ++r) {
            long i = base + r * 256;
            if (i < 320000) reinterpret_cast<f32x4*>(aggN)[i] = f32x4{0.f, 0.f, 0.f, 0.f};
        }
        return;
    }
    __shared__ float sA[2048], sH[2048];
    const int n0 = bid * 32;
    const float* ab = agg + (long)n0 * 64;
    const float* hrow = h + (long)n0 * 64;
    for (int i = tid; i < 2048; i += 256) { sA[i] = ab[i]; sH[i] = hrow[i]; }
    __syncthreads();
    const int u = tid & 63, jg = tid >> 6;
    float xr[8], xz[8], xn[8], hr[8], hz[8], hn[8];
    float b0 = bgx[u], b1 = bgx[64 + u], b2 = bgx[128 + u];
    float d0 = bgh[u], d1 = bgh[64 + u], d2 = bgh[128 + u];
    #pragma unroll
    for (int j = 0; j < 8; ++j) {
        xr[j] = b0; xz[j] = b1; xn[j] = b2;
        hr[j] = d0; hz[j] = d1; hn[j] = d2;
    }
    for (int k = 0; k < 64; ++k) {
        float w0 = Wgx[k * 192 + u], w1 = Wgx[k * 192 + 64 + u], w2 = Wgx[k * 192 + 128 + u];
        float v0 = Wgh[k * 192 + u], v1 = Wgh[k * 192 + 64 + u], v2 = Wgh[k * 192 + 128 + u];
        #pragma unroll
        for (int j = 0; j < 8; ++j) {
            int n = jg * 8 + j;
            float mk = fmaxf(sA[n * 64 + k], 0.f);
            float hk = sH[n * 64 + k];
            xr[j] += mk * w0; xz[j] += mk * w1; xn[j] += mk * w2;
            hr[j] += hk * v0; hz[j] += hk * v1; hn[j] += hk * v2;
        }
    }
    #pragma unroll
    for (int j = 0; j < 8; ++j) {
        int n = jg * 8 + j;
        float rg = sigm(xr[j] + hr[j]);
        float zg = sigm(xz[j] + hz[j]);
        float ng = tanhf(xn[j] + rg * hn[j]);
        long o = (long)(n0 + n) * 64 + u;
        float hv = (1.f - zg) * ng + zg * sH[n * 64 + u];
        hof[o] = hv;
        hb[o] = f2bf(hv);
    }
}

// =============== readout scatter: feat[dst] += [h[src] | relu(ef@Wep+bep)] ===============
__global__ void kreadout(const float* __restrict__ h,
                         const float* __restrict__ ef, const float* __restrict__ Wep,
                         const float* __restrict__ bep,
                         const int* __restrict__ src, const int* __restrict__ dst,
                         float* __restrict__ feat) {
    int t = blockIdx.x * blockDim.x + threadIdx.x;
    if (t >= NE * 128) return;
    int e = t >> 7, j = t & 127;
    float v;
    if (j < 64) {
        v = h[(long)src[e] * 64 + j];
    } else {
        int o = j - 64;
        v = bep[o];
        #pragma unroll
        for (int k = 0; k < 6; ++k) v += ef[(long)e * 6 + k] * Wep[k * 64 + o];
        v = fmaxf(v, 0.f);
    }
    atomicAdd(&feat[(long)dst[e] * 128 + j], v);
}

// =============== klstmattn: one Set2Set iteration (3-layer LSTM + attention), 4 graphs/block ===============
// 200 blocks x 512 threads; optional fused FFN head on the last iteration.
__global__ __launch_bounds__(512) void klstmattn(
    const float* __restrict__ qstar_in, float* __restrict__ qstar_out,
    const float* __restrict__ feat, const int* __restrict__ seg,
    float* __restrict__ esg,
    const float* __restrict__ Wx0, const float* __restrict__ Wh0, const float* __restrict__ bl0,
    const float* __restrict__ Wx1, const float* __restrict__ Wh1, const float* __restrict__ bl1,
    const float* __restrict__ Wx2, const float* __restrict__ Wh2, const float* __restrict__ bl2,
    const float* __restrict__ h0i, const float* __restrict__ c0i, float* __restrict__ h0o, float* __restrict__ c0o,
    const float* __restrict__ h1i, const float* __restrict__ c1i, float* __restrict__ h1o, float* __restrict__ c1o,
    const float* __restrict__ h2i, const float* __restrict__ c2i, float* __restrict__ h2o, float* __restrict__ c2o,
    const float* __restrict__ fpb,
    const float* __restrict__ Wf1, const float* __restrict__ bf1,
    const float* __restrict__ Wf2, const float* __restrict__ bf2,
    const float* __restrict__ Wp, const float* __restrict__ bp,
    float* __restrict__ out, int do_head) {
    __shared__ float gbuf[4][512];     // gates; then attention scratch; then head sx
    __shared__ float sH2[4][128];      // layer-2 h (q)
    __shared__ float s1b[4][300];
    __shared__ float s2[4][256];
    __shared__ float sred[4][2];
    const int tid = threadIdx.x;
    const int b0g = blockIdx.x * 4;
    const float* Wx[3] = {Wx0, Wx1, Wx2};
    const float* Wh[3] = {Wh0, Wh1, Wh2};
    const float* bl[3] = {bl0, bl1, bl2};
    const float* hin[3] = {h0i, h1i, h2i};
    const float* cin[3] = {c0i, c1i, c2i};
    float* hout[3] = {h0o, h1o, h2o};
    float* cout[3] = {c0o, c1o, c2o};

    // ---- 3-layer LSTM (identical math to klstm3) ----
    for (int l = 0; l < 3; ++l) {
        const int Kx = l ? 128 : 256;
        const float* xb = l ? hout[l - 1] : qstar_in;
        const int xstride = l ? 128 : 256;
        const int g = tid;
        float acc[4];
        float bv = bl[l][g];
        #pragma unroll
        for (int b = 0; b < 4; ++b) acc[b] = bv;
        const float* wxp = Wx[l];
        for (int k = 0; k < Kx; ++k) {
            float w = wxp[k * 512 + g];
            #pragma unroll
            for (int b = 0; b < 4; ++b) acc[b] += xb[(long)(b0g + b) * xstride + k] * w;
        }
        const float* whp = Wh[l];
        const float* hrow = hin[l];
        for (int k = 0; k < 128; ++k) {
            float w = whp[k * 512 + g];
            #pragma unroll
            for (int b = 0; b < 4; ++b) acc[b] += hrow[(long)(b0g + b) * 128 + k] * w;
        }
        #pragma unroll
        for (int b = 0; b < 4; ++b) gbuf[b][g] = acc[b];
        __syncthreads();
        {
            int b = tid >> 7, u = tid & 127;
            float gi = gbuf[b][u], gf = gbuf[b][128 + u], gg = gbuf[b][256 + u], go = gbuf[b][384 + u];
            long idx = (long)(b0g + b) * 128 + u;
            float c_ = sigm(gf) * cin[l][idx] + sigm(gi) * tanhf(gg);
            float h_ = sigm(go) * tanhf(c_);
            cout[l][idx] = c_;
            hout[l][idx] = h_;
            if (l == 2) sH2[b][u] = h_;
        }
        __syncthreads();
    }

    // ---- attention: group = tid>>7 handles graph b0g+group with 128 threads ----
    const int group = tid >> 7, j = tid & 127;
    const int s0 = seg[b0g + group], s1 = seg[b0g + group + 1], len = s1 - s0;
    const int wig = j >> 6, lane = j & 63;
    // dot products -> gbuf[group][idx] (global fallback for idx>=512)
    for (int idx = wig; idx < len; idx += 2) {
        long n = s0 + idx;
        float p = feat[n * 128 + lane] * sH2[group][lane]
                + feat[n * 128 + 64 + lane] * sH2[group][64 + lane];
        for (int off = 32; off; off >>= 1) p += __shfl_down(p, off, 64);
        if (lane == 0) { if (idx < 512) gbuf[group][idx] = p; else esg[n] = p; }
    }
    __syncthreads();
    auto ev = [&](int i) { return i < 512 ? gbuf[group][i] : esg[s0 + i]; };
    // max (2 waves per graph)
    float lm = -1e30f;
    for (int i = j; i < len; i += 128) lm = fmaxf(lm, ev(i));
    for (int off = 32; off; off >>= 1) lm = fmaxf(lm, __shfl_down(lm, off, 64));
    if (lane == 0) sred[group][wig] = lm;
    __syncthreads();
    float mx = fmaxf(sred[group][0], sred[group][1]);
    __syncthreads();
    // exp + sum (store exp back)
    float ls = 0.f;
    for (int i = j; i < len; i += 128) {
        float e_ = expf(ev(i) - mx);
        if (i < 512) gbuf[group][i] = e_; else esg[s0 + i] = e_;
        ls += e_;
    }
    for (int off = 32; off; off >>= 1) ls += __shfl_down(ls, off, 64);
    if (lane == 0) sred[group][wig] = ls;
    __syncthreads();
    float inv = 1.f / (sred[group][0] + sred[group][1] + 1e-9f);
    // weighted sum over nodes for feature j
    float racc = 0.f;
    for (int i = 0; i < len; ++i)
        racc += ev(i) * feat[(long)(s0 + i) * 128 + j];
    // write q_star = [q | r]
    qstar_out[(long)(b0g + group) * 256 + j] = sH2[group][j];
    qstar_out[(long)(b0g + group) * 256 + 128 + j] = racc * inv;

    if (!do_head) return;
    __syncthreads();
    // ---- FFN head: comb(384) -> 300 -> 256 -> NTASK ----
    // sx = gbuf (reuse): [g][0..255] = qstar, [g][256..383] = fpb
    {
        if (j < 128) gbuf[group][256 + j] = fpb[(long)(b0g + group) * 128 + j];
        gbuf[group][j] = sH2[group][j];                       // q part
        gbuf[group][128 + j] = racc * inv;                    // r part
    }
    __syncthreads();
    for (int task = tid; task < 1200; task += 512) {
        int g = task / 300, u = task % 300;
        float acc = bf1[u];
        for (int k = 0; k < 384; ++k) acc += gbuf[g][k] * Wf1[k * 300 + u];
        s1b[g][u] = fmaxf(acc, 0.f);
    }
    __syncthreads();
    for (int task = tid; task < 1024; task += 512) {
        int g = task >> 8, u = task & 255;
        float acc = bf2[u];
        for (int k = 0; k < 300; ++k) acc += s1b[g][k] * Wf2[k * 256 + u];
        s2[g][u] = fmaxf(acc, 0.f);
    }
    __syncthreads();
    for (int task = tid; task < 4 * NTASK; task += 512) {
        int g = task / NTASK, u = task % NTASK;
        float acc = bp[u];
        for (int k = 0; k < 256; ++k) acc += s2[g][k] * Wp[k * NTASK + u];
        out[(long)(b0g + g) * NTASK + u] = acc;
    }
}

extern "C" void kernel_launch(void* const* d_in, const int* in_sizes, int n_in,
                              void* d_out, int out_size, void* d_ws, size_t ws_size,
                              hipStream_t stream) {
    auto fp_ = [&](int i) { return (const float*)d_in[i]; };
    auto ip_ = [&](int i) { return (const int*)d_in[i]; };
    const float *nf = fp_(0), *ef = fp_(1), *fpv = fp_(2);
    const int *src = ip_(3), *dst = ip_(4), *gid = ip_(5);
    const float *Wn = fp_(6), *bn = fp_(7), *We1 = fp_(8), *be1 = fp_(9);
    const float *We2 = fp_(10), *be2 = fp_(11), *Wres = fp_(12);
    const float *Wgx = fp_(13), *bgx = fp_(14), *Wgh = fp_(15), *bgh = fp_(16);
    const float *Wep = fp_(17), *bep = fp_(18);
    const float *Wlx0 = fp_(19), *Wlh0 = fp_(20), *bl0 = fp_(21);
    const float *Wlx1 = fp_(22), *Wlh1 = fp_(23), *bl1 = fp_(24);
    const float *Wlx2 = fp_(25), *Wlh2 = fp_(26), *bl2 = fp_(27);
    const float *Wfp = fp_(28), *bfpv = fp_(29);
    const float *bng = fp_(30), *bnb = fp_(31), *bnm = fp_(32), *bnv = fp_(33);
    const float *Wf1 = fp_(34), *bf1 = fp_(35), *Wf2 = fp_(36), *bf2 = fp_(37);
    const float *Wp = fp_(38), *bp = fp_(39);

    char* w = (char*)d_ws;
    auto alloc = [&](size_t bytes) -> char* {
        char* p = w; w += (bytes + 255) & ~(size_t)255; return p;
    };
    float* hA = (float*)alloc((size_t)NN * 64 * 4);
    float* hB = (float*)alloc((size_t)NN * 64 * 4);
    unsigned short* hbA = (unsigned short*)alloc((size_t)NN * 64 * 2);
    unsigned short* hbB = (unsigned short*)alloc((size_t)NN * 64 * 2);
    unsigned short* we2thi = (unsigned short*)alloc((size_t)129 * 4096 * 2);
    float* aggB = (float*)alloc((size_t)NN * 64 * 4);   // zeroed by kgruz
    char* zstart = w;                               // ---- zeroed region start ----
    float* aggA  = (float*)alloc((size_t)NN * 64 * 4);
    float* feat  = (float*)alloc((size_t)NN * 128 * 4);
    float* qstarA = (float*)alloc((size_t)NB * 256 * 4);
    float* qstarB = (float*)alloc((size_t)NB * 256 * 4);
    float* lstmb = (float*)alloc((size_t)12 * NB * 128 * 4);
    size_t zfloats = (size_t)(w - zstart) / 4;      // ---- zeroed region end ----
    float* es   = (float*)alloc((size_t)NN * 4);
    int*   seg  = (int*)alloc((size_t)(NB + 1) * 4);
    float* fpb  = (float*)alloc((size_t)NB * 128 * 4);

    float *hl[3][2], *cl[3][2];
    for (int l = 0; l < 3; ++l)
        for (int a = 0; a < 2; ++a) {
            hl[l][a] = lstmb + ((size_t)(l * 4 + a * 2 + 0)) * NB * 128;
            cl[l][a] = lstmb + ((size_t)(l * 4 + a * 2 + 1)) * NB * 128;
        }

    // --- kpre section boundaries ---
    int nz4 = (int)(zfloats / 4);
    int zb  = (nz4 + 2047) / 2048;
    int B0 = zb;
    int B1 = B0 + 129;            // we2T: 1 block/chunk
    int B2 = B1 + 4;              // seg
    int B3 = B2 + NB;             // fpenc: 1 block/graph
    int B4 = B3 + 1250;           // nodeproj: 16 nodes/block
    kpre<<<B4, 256, 0, stream>>>((float*)zstart, nz4, We2, be2, we2thi, gid, seg,
                                 fpv, Wfp, bfpv, bng, bnb, bnm, bnv, fpb,
                                 nf, Wn, bn, hA, hbA,
                                 B0, B1, B2, B3);

    float* hf[2] = {hA, hB};
    unsigned short* hb[2] = {hbA, hbB};
    float* aggbuf[2] = {aggA, aggB};
    int cur = 0;
    for (int it = 0; it < 3; ++it) {
        float* agg  = aggbuf[it & 1];
        float* aggN = aggbuf[1 - (it & 1)];
        keinsum<<<469 + 625, 256, 0, stream>>>(hb[cur], hf[cur], Wres,
                                               ef, We1, be1, we2thi, src, dst, agg);
        kgruz<<<625 + 157, 256, 0, stream>>>(agg, hf[cur], Wgx, bgx, Wgh, bgh,
                                             hf[1 - cur], hb[1 - cur], aggN);
        cur = 1 - cur;
    }
    kreadout<<<(NE * 128 + 255) / 256, 256, 0, stream>>>(hf[cur], ef, Wep, bep, src, dst, feat);

    float* qs[2] = {qstarA, qstarB};
    for (int t = 0; t < 6; ++t) {
        int a = t & 1;
        klstmattn<<<NB / 4, 512, 0, stream>>>(qs[a], qs[1 - a], feat, seg, es,
            Wlx0, Wlh0, bl0, Wlx1, Wlh1, bl1, Wlx2, Wlh2, bl2,
            hl[0][a], cl[0][a], hl[0][1 - a], cl[0][1 - a],
            hl[1][a], cl[1][a], hl[1][1 - a], cl[1][1 - a],
            hl[2][a], cl[2][a], hl[2][1 - a], cl[2][1 - a],
            fpb, Wf1, bf1, Wf2, bf2, Wp, bp, (float*)d_out, (t == 5) ? 1 : 0);
    }
}

// Round 13
// 1008.881 us; speedup vs baseline: 1.1667x; 1.0288x over previous
//
#include <hip/hip_runtime.h>

typedef short short8 __attribute__((ext_vector_type(8)));
typedef float f32x4  __attribute__((ext_vector_type(4)));

#define NN 20000
#define NE 60000
#define NB 800
#define NTASK 138
#define EB 128   // edges per keinsum block

// bf16 weight buffer offsets (shorts)
#define O_WX0 0
#define O_WH0 131072
#define O_WX1 196608
#define O_WH1 262144
#define O_WX2 327680
#define O_WH2 393216
#define O_WF1 458752
#define O_WF2 573952
#define O_WP  650752
#define NWB   686080

static __device__ __forceinline__ float sigm(float x) { return 1.f / (1.f + expf(-x)); }

static __device__ __forceinline__ unsigned short f2bf(float x) {
    unsigned u = __float_as_uint(x);
    unsigned r = (u + 0x7fffu + ((u >> 16) & 1u)) >> 16;
    return (unsigned short)r;
}
static __device__ __forceinline__ float bf2f(unsigned short b) {
    return __uint_as_float(((unsigned)b) << 16);
}

// =============== kpre: fused [zero | we2T | seg | fpenc | nodeproj | wcvt] ===============
__global__ void kpre(float* __restrict__ zbase, int nz4,
                     const float* __restrict__ We2, const float* __restrict__ be2,
                     unsigned short* __restrict__ thi,
                     const int* __restrict__ gid, int* __restrict__ seg,
                     const float* __restrict__ fpv, const float* __restrict__ Wfp,
                     const float* __restrict__ bfpv,
                     const float* __restrict__ bng, const float* __restrict__ bnb,
                     const float* __restrict__ bnm, const float* __restrict__ bnv,
                     float* __restrict__ fpb,
                     const float* __restrict__ nf, const float* __restrict__ Wn,
                     const float* __restrict__ bn, float* __restrict__ hf,
                     unsigned short* __restrict__ hb,
                     const float* __restrict__ Wlx0, const float* __restrict__ Wlh0,
                     const float* __restrict__ Wlx1, const float* __restrict__ Wlh1,
                     const float* __restrict__ Wlx2, const float* __restrict__ Wlh2,
                     const float* __restrict__ Wf1, const float* __restrict__ Wf2,
                     const float* __restrict__ Wp, unsigned short* __restrict__ wb,
                     int B0, int B1, int B2, int B3, int B4) {
    __shared__ float st[64 * 65];       // we2 transpose tile
    __shared__ float sNF[16 * 134];     // nodeproj staging
    __shared__ float sred[128];
    const int bid = blockIdx.x, tid = threadIdx.x;
    if (bid < B0) {
        long base = (long)bid * 2048 + tid;
        #pragma unroll
        for (int r = 0; r < 8; ++r) {
            long i = base + r * 256;
            if (i < nz4) reinterpret_cast<f32x4*>(zbase)[i] = f32x4{0.f, 0.f, 0.f, 0.f};
        }
    } else if (bid < B1) {
        int c = bid - B0;
        const float* srcp = (c < 128) ? We2 + (long)c * 4096 : be2;
        for (int idx = tid; idx < 4096; idx += 256) {
            int o = idx & 63, i = idx >> 6;
            st[o * 65 + i] = srcp[idx];
        }
        __syncthreads();
        for (int idx = tid; idx < 4096; idx += 256) {
            int i = idx & 63, o = idx >> 6;
            thi[(long)c * 4096 + idx] = f2bf(st[o * 65 + i]);
        }
    } else if (bid < B2) {
        int b = (bid - B1) * 256 + tid;
        if (b <= NB) {
            int lo = 0, hi = NN;
            while (lo < hi) { int mid = (lo + hi) >> 1; if (gid[mid] < b) lo = mid + 1; else hi = mid; }
            seg[b] = lo;
        }
    } else if (bid < B3) {
        int g = bid - B2;
        int u = tid & 127, half = tid >> 7;
        float acc = half ? 0.f : bfpv[u];
        const float* fr = fpv + (long)g * 1024 + half * 512;
        const float* wr = Wfp + (long)half * 512 * 128;
        for (int k = 0; k < 512; ++k) acc += fr[k] * wr[k * 128 + u];
        if (half) sred[u] = acc;
        __syncthreads();
        if (!half) {
            acc += sred[u];
            float sc = bng[u] / sqrtf(bnv[u] + 1e-5f);
            fpb[(long)g * 128 + u] = fmaxf((acc - bnm[u]) * sc + bnb[u], 0.f);
        }
    } else if (bid < B4) {
        int n0 = (bid - B3) * 16;
        const float* nfb = nf + (long)n0 * 134;
        for (int i = tid; i < 16 * 134; i += 256) sNF[i] = nfb[i];
        __syncthreads();
        int u = tid & 63, jg = tid >> 6;
        float a[4];
        float bv = bn[u];
        #pragma unroll
        for (int jj = 0; jj < 4; ++jj) a[jj] = bv;
        for (int k = 0; k < 134; ++k) {
            float w = Wn[k * 64 + u];
            #pragma unroll
            for (int jj = 0; jj < 4; ++jj) a[jj] += sNF[(jg * 4 + jj) * 134 + k] * w;
        }
        #pragma unroll
        for (int jj = 0; jj < 4; ++jj) {
            long o = (long)(n0 + jg * 4 + jj) * 64 + u;
            float v = fmaxf(a[jj], 0.f);
            hf[o] = v;
            hb[o] = f2bf(v);
        }
    } else {
        // weight conversion f32 -> bf16
        int t0 = (bid - B4) * 2048 + tid;
        #pragma unroll
        for (int r = 0; r < 8; ++r) {
            int i = t0 + r * 256;
            if (i >= NWB) break;
            float v;
            if (i < O_WH0)      v = Wlx0[i];
            else if (i < O_WX1) v = Wlh0[i - O_WH0];
            else if (i < O_WH1) v = Wlx1[i - O_WX1];
            else if (i < O_WX2) v = Wlh1[i - O_WH1];
            else if (i < O_WH2) v = Wlx2[i - O_WX2];
            else if (i < O_WF1) v = Wlh2[i - O_WH2];
            else if (i < O_WF2) v = Wf1[i - O_WF1];
            else if (i < O_WP)  v = Wf2[i - O_WF2];
            else                v = Wp[i - O_WP];
            wb[i] = f2bf(v);
        }
    }
}

// =============== keinsum v7 (R10 proven): 128 edges/block, all 129 chunks, fused h@Wres ===============
__global__ __launch_bounds__(256) void keinsum(
    const unsigned short* __restrict__ hb,
    const float* __restrict__ hf, const float* __restrict__ Wres,
    const float* __restrict__ ef, const float* __restrict__ We1, const float* __restrict__ be1,
    const unsigned short* __restrict__ thi,
    const int* __restrict__ src, const int* __restrict__ dst,
    float* __restrict__ agg) {
    __shared__ __align__(16) unsigned short sB[3 * 64 * 72];
    __shared__ __align__(16) float sX[3 * EB];
    __shared__ float sEF[6 * EB];
    const int bid = blockIdx.x, tid = threadIdx.x;
    if (bid >= 469) {
        int t = (bid - 469) * 256 + tid;
        int u = t & 63;
        int n0 = (t >> 6) * 8;
        if (n0 >= NN) return;
        float a[8] = {0.f, 0.f, 0.f, 0.f, 0.f, 0.f, 0.f, 0.f};
        for (int k = 0; k < 64; ++k) {
            float w = Wres[k * 64 + u];
            #pragma unroll
            for (int j = 0; j < 8; ++j) a[j] += hf[(long)(n0 + j) * 64 + k] * w;
        }
        #pragma unroll
        for (int j = 0; j < 8; ++j) atomicAdd(&agg[(long)(n0 + j) * 64 + u], a[j]);
        return;
    }
    const int lane = tid & 63, wave = tid >> 6;
    const int m = lane & 15, q = lane >> 4;
    const int eb = bid * EB;
    const int e0 = eb + wave * 32;
    const int c0 = 0, c1 = 129;

    for (int i = tid; i < 6 * EB; i += 256) {
        int e = i / 6, k = i % 6;
        int ee = eb + e; if (ee >= NE) ee = NE - 1;
        sEF[k * EB + e] = ef[(long)ee * 6 + k];
    }

    short8 ahi[2][2];
    #pragma unroll
    for (int eg = 0; eg < 2; ++eg) {
        int em = e0 + eg * 16 + m; if (em >= NE) em = NE - 1;
        int sn = src[em];
        ahi[eg][0] = *reinterpret_cast<const short8*>(hb + (long)sn * 64 + q * 8);
        ahi[eg][1] = *reinterpret_cast<const short8*>(hb + (long)sn * 64 + 32 + q * 8);
    }
    float msg[2][4][4];
    #pragma unroll
    for (int eg = 0; eg < 2; ++eg)
        #pragma unroll
        for (int nt = 0; nt < 4; ++nt)
            #pragma unroll
            for (int r = 0; r < 4; ++r) msg[eg][nt][r] = 0.f;

    short8 rB[2][2];
    auto GLOAD = [&](int c, int setv) {
        const unsigned short* bb = thi + (long)c * 4096;
        #pragma unroll
        for (int it = 0; it < 2; ++it) {
            int u = tid + it * 256;
            rB[setv][it] = *reinterpret_cast<const short8*>(bb + u * 8);
        }
    };
    auto DSW = [&](int buf, int setv, int c) {
        unsigned short* base = &sB[buf * 4608];
        #pragma unroll
        for (int it = 0; it < 2; ++it) {
            int u = tid + it * 256;
            *reinterpret_cast<short8*>(&base[(u >> 3) * 72 + (u & 7) * 8]) = rB[setv][it];
        }
        if (tid < EB) {
            float xv = 1.f;
            if (c < 128) {
                float a = be1[c];
                #pragma unroll
                for (int k = 0; k < 6; ++k) a += sEF[k * EB + tid] * We1[k * 128 + c];
                xv = fmaxf(a, 0.f);
            }
            sX[buf * EB + tid] = xv;
        }
    };
    auto CMP = [&](int buf) {
        const unsigned short* base = &sB[buf * 4608];
        f32x4 xw[2];
        #pragma unroll
        for (int eg = 0; eg < 2; ++eg)
            xw[eg] = *reinterpret_cast<const f32x4*>(&sX[buf * EB + wave * 32 + eg * 16 + q * 4]);
        short8 b0[4], b1[4];
        #pragma unroll
        for (int nt = 0; nt < 4; ++nt) {
            const unsigned short* rp = &base[(nt * 16 + m) * 72 + q * 8];
            b0[nt] = *reinterpret_cast<const short8*>(rp);
            b1[nt] = *reinterpret_cast<const short8*>(rp + 32);
        }
        #pragma unroll
        for (int eg = 0; eg < 2; ++eg)
            #pragma unroll
            for (int nt = 0; nt < 4; ++nt) {
                f32x4 z = {0.f, 0.f, 0.f, 0.f};
                z = __builtin_amdgcn_mfma_f32_16x16x32_bf16(ahi[eg][0], b0[nt], z, 0, 0, 0);
                z = __builtin_amdgcn_mfma_f32_16x16x32_bf16(ahi[eg][1], b1[nt], z, 0, 0, 0);
                #pragma unroll
                for (int r = 0; r < 4; ++r) msg[eg][nt][r] += xw[eg][r] * z[r];
            }
    };

    GLOAD(c0, 0);
    GLOAD(c0 + 1, 1);
    __syncthreads();
    DSW(0, 0, c0);
    int c = c0;
    for (; c + 1 < c1; c += 2) {
        int s = (c - c0) % 3;
        if (c + 2 < c1) GLOAD(c + 2, 0);
        __syncthreads();
        DSW((s + 1) % 3, 1, c + 1);
        CMP(s);
        if (c + 3 < c1) GLOAD(c + 3, 1);
        __syncthreads();
        if (c + 2 < c1) DSW((s + 2) % 3, 0, c + 2);
        CMP((s + 1) % 3);
    }
    if (c < c1) { __syncthreads(); CMP((c - c0) % 3); }

    #pragma unroll
    for (int eg = 0; eg < 2; ++eg)
        #pragma unroll
        for (int r = 0; r < 4; ++r) {
            int e = e0 + eg * 16 + q * 4 + r;
            if (e < NE) {
                int d = dst[e];
                #pragma unroll
                for (int nt = 0; nt < 4; ++nt)
                    atomicAdd(&agg[(long)d * 64 + nt * 16 + m], msg[eg][nt][r]);
            }
        }
}

// =============== kgruz: LDS-staged GRU (32 nodes/block) + zero next agg ===============
__global__ void kgruz(const float* __restrict__ agg, const float* __restrict__ h,
                      const float* __restrict__ Wgx, const float* __restrict__ bgx,
                      const float* __restrict__ Wgh, const float* __restrict__ bgh,
                      float* __restrict__ hof, unsigned short* __restrict__ hb,
                      float* __restrict__ aggN) {
    const int bid = blockIdx.x, tid = threadIdx.x;
    if (bid >= 625) {
        long base = (long)(bid - 625) * 2048 + tid;
        #pragma unroll
        for (int r = 0; r < 8; ++r) {
            long i = base + r * 256;
            if (i < 320000) reinterpret_cast<f32x4*>(aggN)[i] = f32x4{0.f, 0.f, 0.f, 0.f};
        }
        return;
    }
    __shared__ float sA[2048], sH[2048];
    const int n0 = bid * 32;
    const float* ab = agg + (long)n0 * 64;
    const float* hrow = h + (long)n0 * 64;
    for (int i = tid; i < 2048; i += 256) { sA[i] = ab[i]; sH[i] = hrow[i]; }
    __syncthreads();
    const int u = tid & 63, jg = tid >> 6;
    float xr[8], xz[8], xn[8], hr[8], hz[8], hn[8];
    float b0 = bgx[u], b1 = bgx[64 + u], b2 = bgx[128 + u];
    float d0 = bgh[u], d1 = bgh[64 + u], d2 = bgh[128 + u];
    #pragma unroll
    for (int j = 0; j < 8; ++j) {
        xr[j] = b0; xz[j] = b1; xn[j] = b2;
        hr[j] = d0; hz[j] = d1; hn[j] = d2;
    }
    for (int k = 0; k < 64; ++k) {
        float w0 = Wgx[k * 192 + u], w1 = Wgx[k * 192 + 64 + u], w2 = Wgx[k * 192 + 128 + u];
        float v0 = Wgh[k * 192 + u], v1 = Wgh[k * 192 + 64 + u], v2 = Wgh[k * 192 + 128 + u];
        #pragma unroll
        for (int j = 0; j < 8; ++j) {
            int n = jg * 8 + j;
            float mk = fmaxf(sA[n * 64 + k], 0.f);
            float hk = sH[n * 64 + k];
            xr[j] += mk * w0; xz[j] += mk * w1; xn[j] += mk * w2;
            hr[j] += hk * v0; hz[j] += hk * v1; hn[j] += hk * v2;
        }
    }
    #pragma unroll
    for (int j = 0; j < 8; ++j) {
        int n = jg * 8 + j;
        float rg = sigm(xr[j] + hr[j]);
        float zg = sigm(xz[j] + hz[j]);
        float ng = tanhf(xn[j] + rg * hn[j]);
        long o = (long)(n0 + n) * 64 + u;
        float hv = (1.f - zg) * ng + zg * sH[n * 64 + u];
        hof[o] = hv;
        hb[o] = f2bf(hv);
    }
}

// =============== readout scatter: feat[dst] += [h[src] | relu(ef@Wep+bep)] ===============
__global__ void kreadout(const float* __restrict__ h,
                         const float* __restrict__ ef, const float* __restrict__ Wep,
                         const float* __restrict__ bep,
                         const int* __restrict__ src, const int* __restrict__ dst,
                         float* __restrict__ feat) {
    int t = blockIdx.x * blockDim.x + threadIdx.x;
    if (t >= NE * 128) return;
    int e = t >> 7, j = t & 127;
    float v;
    if (j < 64) {
        v = h[(long)src[e] * 64 + j];
    } else {
        int o = j - 64;
        v = bep[o];
        #pragma unroll
        for (int k = 0; k < 6; ++k) v += ef[(long)e * 6 + k] * Wep[k * 64 + o];
        v = fmaxf(v, 0.f);
    }
    atomicAdd(&feat[(long)dst[e] * 128 + j], v);
}

// =============== klstmattn: one Set2Set iteration (3-layer LSTM + attention), 4 graphs/block ===============
// bf16 weights; optional fused FFN head on the last iteration.
__global__ __launch_bounds__(512) void klstmattn(
    const float* __restrict__ qstar_in, float* __restrict__ qstar_out,
    const float* __restrict__ feat, const int* __restrict__ seg,
    float* __restrict__ esg,
    const unsigned short* __restrict__ wb,
    const float* __restrict__ bl0, const float* __restrict__ bl1, const float* __restrict__ bl2,
    const float* __restrict__ h0i, const float* __restrict__ c0i, float* __restrict__ h0o, float* __restrict__ c0o,
    const float* __restrict__ h1i, const float* __restrict__ c1i, float* __restrict__ h1o, float* __restrict__ c1o,
    const float* __restrict__ h2i, const float* __restrict__ c2i, float* __restrict__ h2o, float* __restrict__ c2o,
    const float* __restrict__ fpb,
    const float* __restrict__ bf1, const float* __restrict__ bf2, const float* __restrict__ bp,
    float* __restrict__ out, int do_head) {
    __shared__ float gbuf[4][512];     // gates; then attention scratch; then head sx
    __shared__ float sH2[4][128];      // layer-2 h (q)
    __shared__ float s1b[4][300];
    __shared__ float s2[4][256];
    __shared__ float sred[4][2];
    const int tid = threadIdx.x;
    const int b0g = blockIdx.x * 4;
    const unsigned short* Wx[3] = {wb + O_WX0, wb + O_WX1, wb + O_WX2};
    const unsigned short* Wh[3] = {wb + O_WH0, wb + O_WH1, wb + O_WH2};
    const float* bl[3] = {bl0, bl1, bl2};
    const float* hin[3] = {h0i, h1i, h2i};
    const float* cin[3] = {c0i, c1i, c2i};
    float* hout[3] = {h0o, h1o, h2o};
    float* cout[3] = {c0o, c1o, c2o};

    // ---- 3-layer LSTM ----
    for (int l = 0; l < 3; ++l) {
        const int Kx = l ? 128 : 256;
        const float* xb = l ? hout[l - 1] : qstar_in;
        const int xstride = l ? 128 : 256;
        const int g = tid;
        float acc[4];
        float bv = bl[l][g];
        #pragma unroll
        for (int b = 0; b < 4; ++b) acc[b] = bv;
        const unsigned short* wxp = Wx[l];
        for (int k = 0; k < Kx; ++k) {
            float w = bf2f(wxp[k * 512 + g]);
            #pragma unroll
            for (int b = 0; b < 4; ++b) acc[b] += xb[(long)(b0g + b) * xstride + k] * w;
        }
        const unsigned short* whp = Wh[l];
        const float* hrow = hin[l];
        for (int k = 0; k < 128; ++k) {
            float w = bf2f(whp[k * 512 + g]);
            #pragma unroll
            for (int b = 0; b < 4; ++b) acc[b] += hrow[(long)(b0g + b) * 128 + k] * w;
        }
        #pragma unroll
        for (int b = 0; b < 4; ++b) gbuf[b][g] = acc[b];
        __syncthreads();
        {
            int b = tid >> 7, u = tid & 127;
            float gi = gbuf[b][u], gf = gbuf[b][128 + u], gg = gbuf[b][256 + u], go = gbuf[b][384 + u];
            long idx = (long)(b0g + b) * 128 + u;
            float c_ = sigm(gf) * cin[l][idx] + sigm(gi) * tanhf(gg);
            float h_ = sigm(go) * tanhf(c_);
            cout[l][idx] = c_;
            hout[l][idx] = h_;
            if (l == 2) sH2[b][u] = h_;
        }
        __syncthreads();
    }

    // ---- attention ----
    const int group = tid >> 7, j = tid & 127;
    const int s0 = seg[b0g + group], s1 = seg[b0g + group + 1], len = s1 - s0;
    const int wig = j >> 6, lane = j & 63;
    for (int idx = wig; idx < len; idx += 2) {
        long n = s0 + idx;
        float p = feat[n * 128 + lane] * sH2[group][lane]
                + feat[n * 128 + 64 + lane] * sH2[group][64 + lane];
        for (int off = 32; off; off >>= 1) p += __shfl_down(p, off, 64);
        if (lane == 0) { if (idx < 512) gbuf[group][idx] = p; else esg[n] = p; }
    }
    __syncthreads();
    auto ev = [&](int i) { return i < 512 ? gbuf[group][i] : esg[s0 + i]; };
    float lm = -1e30f;
    for (int i = j; i < len; i += 128) lm = fmaxf(lm, ev(i));
    for (int off = 32; off; off >>= 1) lm = fmaxf(lm, __shfl_down(lm, off, 64));
    if (lane == 0) sred[group][wig] = lm;
    __syncthreads();
    float mx = fmaxf(sred[group][0], sred[group][1]);
    __syncthreads();
    float ls = 0.f;
    for (int i = j; i < len; i += 128) {
        float e_ = expf(ev(i) - mx);
        if (i < 512) gbuf[group][i] = e_; else esg[s0 + i] = e_;
        ls += e_;
    }
    for (int off = 32; off; off >>= 1) ls += __shfl_down(ls, off, 64);
    if (lane == 0) sred[group][wig] = ls;
    __syncthreads();
    float inv = 1.f / (sred[group][0] + sred[group][1] + 1e-9f);
    float racc = 0.f;
    for (int i = 0; i < len; ++i)
        racc += ev(i) * feat[(long)(s0 + i) * 128 + j];
    qstar_out[(long)(b0g + group) * 256 + j] = sH2[group][j];
    qstar_out[(long)(b0g + group) * 256 + 128 + j] = racc * inv;

    if (!do_head) return;
    __syncthreads();
    // ---- FFN head (bf16 weights): comb(384) -> 300 -> 256 -> NTASK ----
    {
        if (j < 128) gbuf[group][256 + j] = fpb[(long)(b0g + group) * 128 + j];
        gbuf[group][j] = sH2[group][j];
        gbuf[group][128 + j] = racc * inv;
    }
    __syncthreads();
    const unsigned short* Wf1b = wb + O_WF1;
    const unsigned short* Wf2b = wb + O_WF2;
    const unsigned short* Wpb  = wb + O_WP;
    for (int task = tid; task < 1200; task += 512) {
        int g = task / 300, u = task % 300;
        float acc = bf1[u];
        for (int k = 0; k < 384; ++k) acc += gbuf[g][k] * bf2f(Wf1b[k * 300 + u]);
        s1b[g][u] = fmaxf(acc, 0.f);
    }
    __syncthreads();
    for (int task = tid; task < 1024; task += 512) {
        int g = task >> 8, u = task & 255;
        float acc = bf2[u];
        for (int k = 0; k < 300; ++k) acc += s1b[g][k] * bf2f(Wf2b[k * 256 + u]);
        s2[g][u] = fmaxf(acc, 0.f);
    }
    __syncthreads();
    for (int task = tid; task < 4 * NTASK; task += 512) {
        int g = task / NTASK, u = task % NTASK;
        float acc = bp[u];
        for (int k = 0; k < 256; ++k) acc += s2[g][k] * bf2f(Wpb[k * NTASK + u]);
        out[(long)(b0g + g) * NTASK + u] = acc;
    }
}

extern "C" void kernel_launch(void* const* d_in, const int* in_sizes, int n_in,
                              void* d_out, int out_size, void* d_ws, size_t ws_size,
                              hipStream_t stream) {
    auto fp_ = [&](int i) { return (const float*)d_in[i]; };
    auto ip_ = [&](int i) { return (const int*)d_in[i]; };
    const float *nf = fp_(0), *ef = fp_(1), *fpv = fp_(2);
    const int *src = ip_(3), *dst = ip_(4), *gid = ip_(5);
    const float *Wn = fp_(6), *bn = fp_(7), *We1 = fp_(8), *be1 = fp_(9);
    const float *We2 = fp_(10), *be2 = fp_(11), *Wres = fp_(12);
    const float *Wgx = fp_(13), *bgx = fp_(14), *Wgh = fp_(15), *bgh = fp_(16);
    const float *Wep = fp_(17), *bep = fp_(18);
    const float *Wlx0 = fp_(19), *Wlh0 = fp_(20), *bl0 = fp_(21);
    const float *Wlx1 = fp_(22), *Wlh1 = fp_(23), *bl1 = fp_(24);
    const float *Wlx2 = fp_(25), *Wlh2 = fp_(26), *bl2 = fp_(27);
    const float *Wfp = fp_(28), *bfpv = fp_(29);
    const float *bng = fp_(30), *bnb = fp_(31), *bnm = fp_(32), *bnv = fp_(33);
    const float *Wf1 = fp_(34), *bf1 = fp_(35), *Wf2 = fp_(36), *bf2 = fp_(37);
    const float *Wp = fp_(38), *bp = fp_(39);

    char* w = (char*)d_ws;
    auto alloc = [&](size_t bytes) -> char* {
        char* p = w; w += (bytes + 255) & ~(size_t)255; return p;
    };
    float* hA = (float*)alloc((size_t)NN * 64 * 4);
    float* hB = (float*)alloc((size_t)NN * 64 * 4);
    unsigned short* hbA = (unsigned short*)alloc((size_t)NN * 64 * 2);
    unsigned short* hbB = (unsigned short*)alloc((size_t)NN * 64 * 2);
    unsigned short* we2thi = (unsigned short*)alloc((size_t)129 * 4096 * 2);
    unsigned short* wbf = (unsigned short*)alloc((size_t)NWB * 2);
    float* aggB = (float*)alloc((size_t)NN * 64 * 4);   // zeroed by kgruz
    char* zstart = w;                               // ---- zeroed region start ----
    float* aggA  = (float*)alloc((size_t)NN * 64 * 4);
    float* feat  = (float*)alloc((size_t)NN * 128 * 4);
    float* qstarA = (float*)alloc((size_t)NB * 256 * 4);
    float* qstarB = (float*)alloc((size_t)NB * 256 * 4);
    float* lstmb = (float*)alloc((size_t)12 * NB * 128 * 4);
    size_t zfloats = (size_t)(w - zstart) / 4;      // ---- zeroed region end ----
    float* es   = (float*)alloc((size_t)NN * 4);
    int*   seg  = (int*)alloc((size_t)(NB + 1) * 4);
    float* fpb  = (float*)alloc((size_t)NB * 128 * 4);

    float *hl[3][2], *cl[3][2];
    for (int l = 0; l < 3; ++l)
        for (int a = 0; a < 2; ++a) {
            hl[l][a] = lstmb + ((size_t)(l * 4 + a * 2 + 0)) * NB * 128;
            cl[l][a] = lstmb + ((size_t)(l * 4 + a * 2 + 1)) * NB * 128;
        }

    // --- kpre section boundaries ---
    int nz4 = (int)(zfloats / 4);
    int zb  = (nz4 + 2047) / 2048;
    int B0 = zb;
    int B1 = B0 + 129;            // we2T: 1 block/chunk
    int B2 = B1 + 4;              // seg
    int B3 = B2 + NB;             // fpenc: 1 block/graph
    int B4 = B3 + 1250;           // nodeproj: 16 nodes/block
    int B5 = B4 + (NWB + 2047) / 2048;  // weight conversion
    kpre<<<B5, 256, 0, stream>>>((float*)zstart, nz4, We2, be2, we2thi, gid, seg,
                                 fpv, Wfp, bfpv, bng, bnb, bnm, bnv, fpb,
                                 nf, Wn, bn, hA, hbA,
                                 Wlx0, Wlh0, Wlx1, Wlh1, Wlx2, Wlh2, Wf1, Wf2, Wp, wbf,
                                 B0, B1, B2, B3, B4);

    float* hf[2] = {hA, hB};
    unsigned short* hb[2] = {hbA, hbB};
    float* aggbuf[2] = {aggA, aggB};
    int cur = 0;
    for (int it = 0; it < 3; ++it) {
        float* agg  = aggbuf[it & 1];
        float* aggN = aggbuf[1 - (it & 1)];
        keinsum<<<469 + 625, 256, 0, stream>>>(hb[cur], hf[cur], Wres,
                                               ef, We1, be1, we2thi, src, dst, agg);
        kgruz<<<625 + 157, 256, 0, stream>>>(agg, hf[cur], Wgx, bgx, Wgh, bgh,
                                             hf[1 - cur], hb[1 - cur], aggN);
        cur = 1 - cur;
    }
    kreadout<<<(NE * 128 + 255) / 256, 256, 0, stream>>>(hf[cur], ef, Wep, bep, src, dst, feat);

    float* qs[2] = {qstarA, qstarB};
    for (int t = 0; t < 6; ++t) {
        int a = t & 1;
        klstmattn<<<NB / 4, 512, 0, stream>>>(qs[a], qs[1 - a], feat, seg, es,
            wbf, bl0, bl1, bl2,
            hl[0][a], cl[0][a], hl[0][1 - a], cl[0][1 - a],
            hl[1][a], cl[1][a], hl[1][1 - a], cl[1][1 - a],
            hl[2][a], cl[2][a], hl[2][1 - a], cl[2][1 - a],
            fpb, bf1, bf2, bp, (float*)d_out, (t == 5) ? 1 : 0);
    }
}